// Round 3
// baseline (127.155 us; speedup 1.0000x reference)
//
#include <hip/hip_runtime.h>
#include <hip/hip_bf16.h>

typedef unsigned int u32;
typedef unsigned long long u64;
typedef __attribute__((ext_vector_type(8))) short bf16x8;
typedef __attribute__((ext_vector_type(4))) float f32x4;
typedef __attribute__((ext_vector_type(4))) u32 u32x4;

#define NB 128
#define PP 200
#define KK 60
#define NN (NB*PP)      // 25600
#define HH 64
#define TW 2            // targets per wave
#define NWV 5           // waves per block
#define TB (TW*NWV)     // 10 targets per block
#define BPE (PP/TB)     // 20 blocks per event
#define NTHREADS (NWV*64)

// d_out is FLOAT32. Offsets in f32 elements: out, pos, batch, edge(src,dst)
#define OUT_OFF   0
#define POS_OFF   (NN*HH)             // 1638400
#define BATCH_OFF (POS_OFF + NN*3)    // 1715200
#define ESRC_OFF  (BATCH_OFF + NN)    // 1740800
#define EDST_OFF  (ESRC_OFF + NN*KK)  // 3276800

// truncating bf16x2 pack in ONE v_perm_b32: D = (hi16 of b)<<16 | (hi16 of a)
static __device__ __forceinline__ u32 packtr(float a, float b) {
    return __builtin_amdgcn_perm(__float_as_uint(b), __float_as_uint(a), 0x07060302u);
}
static __device__ __forceinline__ u32 prefix_lt(u64 b) {   // #set bits below lane
    return __builtin_amdgcn_mbcnt_hi((u32)(b >> 32),
                                     __builtin_amdgcn_mbcnt_lo((u32)b, 0));
}
// xor-16 then xor-32 max butterfly entirely on the VALU pipe (no ds_swizzle)
static __device__ __forceinline__ float wavemax16(float v) {
    u32 x = __float_as_uint(v);
    auto p16 = __builtin_amdgcn_permlane16_swap(x, x, false, false);
    float m = fmaxf(__uint_as_float(p16[0]), __uint_as_float(p16[1]));
    u32 y = __float_as_uint(m);
    auto p32 = __builtin_amdgcn_permlane32_swap(y, y, false, false);
    return fmaxf(__uint_as_float(p32[0]), __uint_as_float(p32[1]));
}

// ---------------------------------------------------------------------------
// FUSED kernel: block = 10 targets of one event; 5 waves x 2 targets.
// R2 post-mortem: latency-bound, not throughput-bound. This round: back to
// best-measured TW=2 wave shape, 5-wave blocks + grid 2560 for occupancy,
// batched msg writes (one LDS round trip/wave), permlane max-butterflies
// (off the LDS pipe), setprio around MFMA clusters.
// ---------------------------------------------------------------------------
__global__ __launch_bounds__(NTHREADS) void fused_kernel(const float* __restrict__ x,
                                                    const float* __restrict__ pos,
                                                    const float* __restrict__ W1,
                                                    const float* __restrict__ b1p,
                                                    const float* __restrict__ W2,
                                                    const float* __restrict__ b2p,
                                                    float* __restrict__ out) {
    __shared__ alignas(16) float xs[PP * 4];          // 3200 B
    __shared__ alignas(16) float psl[PP * 3];         // 2400 B
    __shared__ alignas(16) u32 jslot[NWV * TW * 64];  // 2560 B
    __shared__ alignas(16) u32 msg[NWV * TW * 256];   // 10240 B
    __shared__ alignas(16) u32 pkW1[64 * 4];          // 1024 B
    __shared__ alignas(16) u32 pkW2T[64 * 33];        // 8448 B (stride 33: conflict-free)
    __shared__ alignas(16) float b2s[64];             // 256 B
    __shared__ alignas(16) u32 zrow[4];               // 16 B zero B-frag row

    int tid = threadIdx.x, blk = blockIdx.x;
    int e = blk / BPE;
    int pl0b = (blk % BPE) * TB;
    int i0b  = e * PP + pl0b;

    // pos/batch passthrough straight from global (no barrier dependency)
    if (tid < 3*TB) out[POS_OFF + i0b * 3 + tid] = pos[i0b * 3 + tid];
    if (tid < TB)   out[BATCH_OFF + i0b + tid] = (float)e;

    if (tid < 200) ((f32x4*)xs)[tid]  = ((const f32x4*)x)[e * PP + tid];
    if (tid < 150) ((f32x4*)psl)[tid] = ((const f32x4*)pos)[e * 150 + tid];
    if (tid < 4)   zrow[tid] = 0u;

    // ---- block-level packed-weight staging ----
    if (tid < 256) {   // pkW1: 256 entries: m = tid&63, d = tid>>6
        int m = tid & 63, d = tid >> 6;
        float hiv = (d < 3) ? W1[(2*d + 1)*64 + m] : b1p[m];   // bias in slot 7
        pkW1[m*4 + d] = packtr(W1[(2*d)*64 + m], hiv);
    }
    #pragma unroll
    for (int r = 0; r < 4; ++r) {                 // pkW2T via vectorized f32x4 loads
        int g = r * NTHREADS + tid;               // need [0,1024): kp in [0,32), colq in [0,16)
        if (g < 1024) {
            int kp = g >> 4, colq = g & 15;
            f32x4 ra = *(const f32x4*)&W2[(2*kp)    *64 + colq*4];
            f32x4 rb = *(const f32x4*)&W2[(2*kp + 1)*64 + colq*4];
            #pragma unroll
            for (int c = 0; c < 4; ++c)
                pkW2T[(colq*4 + c)*33 + kp] = packtr(ra[c], rb[c]);
        }
    }
    if (tid < 64) b2s[tid] = b2p[tid];
    __syncthreads();

    int lane = tid & 63, wv = tid >> 6;
    int lo16 = lane & 15, hi16 = lane >> 4;
    int plW0 = pl0b + wv * TW;
    int iW0  = e * PP + plW0;

    // ---------------- Phase B: KNN for two targets ----------------
    u32 key[TW][4];
    {
        float ax[TW], ay[TW], az[TW];
        #pragma unroll
        for (int t = 0; t < TW; ++t) {
            ax[t] = psl[(plW0+t)*3]; ay[t] = psl[(plW0+t)*3+1]; az[t] = psl[(plW0+t)*3+2];
        }
        #pragma unroll
        for (int q = 0; q < 4; ++q) {
            int j = lane + q * 64;
            int jc = (j < PP) ? j : 0;
            float px = psl[jc*3], py = psl[jc*3+1], pz = psl[jc*3+2];
            #pragma unroll
            for (int t = 0; t < TW; ++t) {
                float dx = px-ax[t], dy = py-ay[t], dz = pz-az[t];
                float d2 = dx*dx + dy*dy + dz*dz;
                key[t][q] = (j < PP && j != plW0 + t)
                          ? ((__float_as_uint(d2) & 0xFFFFFF00u) | (u32)j) : 0xFFFFFFFFu;
            }
        }
    }

    // interleaved skip-done ballot bisection; exit on cnt==60 or width<=1
    u32 lo[TW], hi[TW]; int done[TW];
    #pragma unroll
    for (int t = 0; t < TW; ++t) { lo[t] = 0u; hi[t] = 0x7F800000u; done[t] = 0; }
    #pragma unroll 1
    for (int it = 0; it < 40; ++it) {
        #pragma unroll
        for (int t = 0; t < TW; ++t) {
            if (!done[t]) {
                u32 m = lo[t] + ((hi[t] - lo[t]) >> 1);
                int c = __builtin_popcountll(__ballot(key[t][0] < m))
                      + __builtin_popcountll(__ballot(key[t][1] < m))
                      + __builtin_popcountll(__ballot(key[t][2] < m))
                      + __builtin_popcountll(__ballot(key[t][3] < m));
                if (c >= KK) hi[t] = m; else lo[t] = m;
                done[t] = (c == KK) | (hi[t] - lo[t] <= 1u);
            }
        }
        int alldone = done[0];
        #pragma unroll
        for (int t = 1; t < TW; ++t) alldone &= done[t];
        if (alldone) break;
    }

    const int jsb = wv * (TW * 64);
    #pragma unroll
    for (int t = 0; t < TW; ++t) {
        if (lane >= KK) jslot[jsb + t * 64 + lane] = (u32)(plW0 + t);  // self slots
        u64 m0 = __ballot(key[t][0] < hi[t]);
        u64 m1 = __ballot(key[t][1] < hi[t]);
        u64 m2 = __ballot(key[t][2] < hi[t]);
        u64 m3 = __ballot(key[t][3] < hi[t]);
        u32 s1 = (u32)__builtin_popcountll(m0);
        u32 s2 = s1 + (u32)__builtin_popcountll(m1);
        u32 s3 = s2 + (u32)__builtin_popcountll(m2);
        u32 sl[4] = { prefix_lt(m0), s1 + prefix_lt(m1),
                      s2 + prefix_lt(m2), s3 + prefix_lt(m3) };
        #pragma unroll
        for (int q = 0; q < 4; ++q)
            if (key[t][q] < hi[t]) jslot[jsb + t * 64 + (int)sl[q]] = key[t][q] & 0xFFu;
    }
    // coalesced edge outputs from jslot
    #pragma unroll
    for (int t = 0; t < TW; ++t) {
        int i = iW0 + t;
        if (lane < KK) {
            out[ESRC_OFF + i * KK + lane] = (float)(e * PP + (int)jslot[jsb + t * 64 + lane]);
            out[EDST_OFF + i * KK + lane] = (float)i;
        }
    }

    // ---------------- weights: per-wave fragment loads from LDS ----------------
    bf16x8 w1f[4];
    #pragma unroll
    for (int th = 0; th < 4; ++th) {
        union { u32 w[4]; bf16x8 v; } u;
        if (hi16 == 0) *(u32x4*)u.w = *(const u32x4*)&pkW1[(th * 16 + lo16) * 4];
        else { u.w[0] = u.w[1] = u.w[2] = u.w[3] = 0u; }
        w1f[th] = u.v;
    }
    bf16x8 bfr[4][2];
    #pragma unroll
    for (int t = 0; t < 4; ++t)
        #pragma unroll
        for (int s = 0; s < 2; ++s) {
            union { u32 w[4]; bf16x8 v; } u;
            int base = (t * 16 + lo16) * 33 + s * 16 + hi16 * 4;
            #pragma unroll
            for (int d = 0; d < 4; ++d) u.w[d] = pkW2T[base + d];
            bfr[t][s] = u.v;
        }
    float b2me = b2s[lane];                       // this lane's output column bias

    // ---------------- Phase C: MLP + max-aggregate ----------------
    const int msb = wv * (TW * 256);
    // batch BOTH targets' msg rows first -> single LDS round trip per wave
    #pragma unroll
    for (int tl = 0; tl < TW; ++tl) {
        int pl = plW0 + tl;
        int jloc = (int)jslot[jsb + tl * 64 + lane];
        f32x4 xv = ((const f32x4*)xs)[jloc];
        float rx = psl[jloc*3]   - psl[pl*3];
        float ry = psl[jloc*3+1] - psl[pl*3+1];
        float rz = psl[jloc*3+2] - psl[pl*3+2];
        u32x4 mrow;
        mrow[0] = packtr(xv[0], xv[1]);
        mrow[1] = packtr(xv[2], xv[3]);
        mrow[2] = packtr(rx, ry);
        mrow[3] = packtr(rz, 1.0f);
        *(u32x4*)&msg[msb + tl * 256 + lane * 4] = mrow;
    }

    #pragma unroll
    for (int tl = 0; tl < TW; ++tl) {
        int i = iW0 + tl;
        const u32* mbase = (hi16 == 0) ? &msg[msb + tl * 256 + lo16 * 4] : zrow;
        const int mstep  = (hi16 == 0) ? 64 : 0;

        float rmax[4] = {-3.0e38f, -3.0e38f, -3.0e38f, -3.0e38f};
        __builtin_amdgcn_s_setprio(1);
        #pragma unroll
        for (int rt = 0; rt < 4; ++rt) {
            union { u32 w[4]; bf16x8 v; } mu;
            *(u32x4*)mu.w = *(const u32x4*)(mbase + rt * mstep);

            f32x4 c1[4];
            #pragma unroll
            for (int th = 0; th < 4; ++th)
                c1[th] = __builtin_amdgcn_mfma_f32_16x16x32_bf16(w1f[th], mu.v,
                                                                 (f32x4)0.f, 0, 0, 0);
            f32x4 acc[4];
            #pragma unroll
            for (int t = 0; t < 4; ++t) acc[t] = (f32x4)0.f;

            #pragma unroll
            for (int s = 0; s < 2; ++s) {
                u32 pe0 = packtr(fmaxf(c1[2*s][0], 0.f), fmaxf(c1[2*s][1], 0.f));
                u32 pe1 = packtr(fmaxf(c1[2*s][2], 0.f), fmaxf(c1[2*s][3], 0.f));
                u32 po0 = packtr(fmaxf(c1[2*s+1][0], 0.f), fmaxf(c1[2*s+1][1], 0.f));
                u32 po1 = packtr(fmaxf(c1[2*s+1][2], 0.f), fmaxf(c1[2*s+1][3], 0.f));
                // register repack (permlane32_swap + permlane16_swap), no LDS
                union { u32 w[4]; bf16x8 v; } u;
                {
                    auto t0 = __builtin_amdgcn_permlane32_swap(pe0, po0, false, false);
                    auto w0 = __builtin_amdgcn_permlane16_swap(t0[0], t0[1], false, false);
                    u.w[0] = w0[0]; u.w[2] = w0[1];
                }
                {
                    auto t1 = __builtin_amdgcn_permlane32_swap(pe1, po1, false, false);
                    auto w1 = __builtin_amdgcn_permlane16_swap(t1[0], t1[1], false, false);
                    u.w[1] = w1[0]; u.w[3] = w1[1];
                }
                #pragma unroll
                for (int t = 0; t < 4; ++t)
                    acc[t] = __builtin_amdgcn_mfma_f32_16x16x32_bf16(u.v, bfr[t][s],
                                                                     acc[t], 0, 0, 0);
            }
            #pragma unroll
            for (int t = 0; t < 4; ++t) {
                rmax[t] = fmaxf(fmaxf(acc[t][0], acc[t][1]), rmax[t]);
                rmax[t] = fmaxf(fmaxf(acc[t][2], acc[t][3]), rmax[t]);
            }
        }
        __builtin_amdgcn_s_setprio(0);
        // VALU-pipe max butterflies (xor16 then xor32)
        #pragma unroll
        for (int t = 0; t < 4; ++t) rmax[t] = wavemax16(rmax[t]);
        float sel = rmax[0];
        sel = (hi16 == 1) ? rmax[1] : sel;
        sel = (hi16 == 2) ? rmax[2] : sel;
        sel = (hi16 == 3) ? rmax[3] : sel;
        out[OUT_OFF + i * 64 + lane] = fmaxf(sel + b2me, 0.f);
    }
}

// ---------------------------------------------------------------------------
extern "C" void kernel_launch(void* const* d_in, const int* in_sizes, int n_in,
                              void* d_out, int out_size, void* d_ws, size_t ws_size,
                              hipStream_t stream) {
    const float* x     = (const float*)d_in[0];
    const float* pos   = (const float*)d_in[1];
    const float* W1    = (const float*)d_in[3];
    const float* b1    = (const float*)d_in[4];
    const float* W2    = (const float*)d_in[5];
    const float* b2    = (const float*)d_in[6];
    float* out = (float*)d_out;
    (void)d_ws; (void)ws_size; (void)in_sizes; (void)n_in; (void)out_size;

    fused_kernel<<<dim3(NN / TB), dim3(NTHREADS), 0, stream>>>(x, pos, W1, b1, W2, b2, out);
}

// Round 5
// 113.729 us; speedup vs baseline: 1.1180x; 1.1180x over previous
//
#include <hip/hip_runtime.h>
#include <hip/hip_bf16.h>

typedef unsigned int u32;
typedef unsigned long long u64;
typedef __attribute__((ext_vector_type(8))) short bf16x8;
typedef __attribute__((ext_vector_type(4))) float f32x4;
typedef __attribute__((ext_vector_type(4))) u32 u32x4;
typedef __attribute__((ext_vector_type(2))) u32 u32x2;

#define NB 128
#define PP 200
#define KK 60
#define NN (NB*PP)      // 25600
#define HH 64
#define TW 2            // targets per wave
#define NWV 4           // waves per block
#define TB (TW*NWV)     // 8 targets per block
#define BPE (PP/TB)     // 25 blocks per event
#define NTHREADS (NWV*64)

// d_out is FLOAT32. Offsets in f32 elements: out, pos, batch, edge(src,dst)
#define OUT_OFF   0
#define POS_OFF   (NN*HH)             // 1638400
#define BATCH_OFF (POS_OFF + NN*3)    // 1715200
#define ESRC_OFF  (BATCH_OFF + NN)    // 1740800
#define EDST_OFF  (ESRC_OFF + NN*KK)  // 3276800

// truncating bf16x2 pack in ONE v_perm_b32: D = (hi16 of b)<<16 | (hi16 of a)
static __device__ __forceinline__ u32 packtr(float a, float b) {
    return __builtin_amdgcn_perm(__float_as_uint(b), __float_as_uint(a), 0x07060302u);
}
static __device__ __forceinline__ u32 prefix_lt(u64 b) {   // #set bits below lane
    return __builtin_amdgcn_mbcnt_hi((u32)(b >> 32),
                                     __builtin_amdgcn_mbcnt_lo((u32)b, 0));
}
// xor-16 then xor-32 max butterfly entirely on the VALU pipe (no ds_swizzle)
static __device__ __forceinline__ float wavemax16(float v) {
    u32 x = __float_as_uint(v);
    auto p16 = __builtin_amdgcn_permlane16_swap(x, x, false, false);
    float m = fmaxf(__uint_as_float(p16[0]), __uint_as_float(p16[1]));
    u32 y = __float_as_uint(m);
    auto p32 = __builtin_amdgcn_permlane32_swap(y, y, false, false);
    return fmaxf(__uint_as_float(p32[0]), __uint_as_float(p32[1]));
}

// ---------------------------------------------------------------------------
// R4 (resubmit; prior run was an infra failure): best-measured shape
// (256 thr, 4 waves, TW=2, grid 3200) with LDS trimmed to 19.9KB
// (8-block/32-wave cap), weight-frag loads hoisted under the search chain,
// branchless unroll-4 bisection. Latency-bound diagnosis: dur*occupancy ~
// const across R0-R3; throughput = resident waves / wave lifetime.
// ---------------------------------------------------------------------------
__global__ __launch_bounds__(NTHREADS) void fused_kernel(const float* __restrict__ x,
                                                    const float* __restrict__ pos,
                                                    const float* __restrict__ W1,
                                                    const float* __restrict__ b1p,
                                                    const float* __restrict__ W2,
                                                    const float* __restrict__ b2p,
                                                    float* __restrict__ out) {
    __shared__ alignas(16) u32 xsp[PP * 2];           // 1600 B  x rows pre-packed bf16x2
    __shared__ alignas(16) float psl[PP * 3];         // 2400 B
    __shared__ alignas(16) u32 jslot[NWV * TW * 64];  // 2048 B
    __shared__ alignas(16) u32 msg[NWV * 256];        // 4096 B (per-tl reuse)
    __shared__ alignas(16) u32 pkW1[64 * 4];          // 1024 B
    __shared__ alignas(16) u32 pkW2T[64 * 33];        // 8448 B (stride 33: conflict-free)
    __shared__ alignas(16) float b2s[64];             // 256 B
    __shared__ alignas(16) u32 zrow[4];               // 16 B zero B-frag row
    // total = 19,888 B  ->  8 blocks/CU (32-wave cap)

    int tid = threadIdx.x, blk = blockIdx.x;
    int e = blk / BPE;
    int pl0b = (blk % BPE) * TB;
    int i0b  = e * PP + pl0b;

    // pos/batch passthrough straight from global (no barrier dependency)
    if (tid < 3*TB) out[POS_OFF + i0b * 3 + tid] = pos[i0b * 3 + tid];
    if (tid < TB)   out[BATCH_OFF + i0b + tid] = (float)e;

    if (tid < 200) {                                  // x staged already bf16-packed
        f32x4 xv = ((const f32x4*)x)[e * PP + tid];
        u32x2 p; p[0] = packtr(xv[0], xv[1]); p[1] = packtr(xv[2], xv[3]);
        *(u32x2*)&xsp[tid * 2] = p;
    }
    if (tid < 150) ((f32x4*)psl)[tid] = ((const f32x4*)pos)[e * 150 + tid];
    if (tid < 4)   zrow[tid] = 0u;

    // ---- block-level packed-weight staging ----
    {   // pkW1: 256 entries: m = tid&63, d = tid>>6
        int m = tid & 63, d = tid >> 6;
        float hiv = (d < 3) ? W1[(2*d + 1)*64 + m] : b1p[m];   // bias in slot 7
        pkW1[m*4 + d] = packtr(W1[(2*d)*64 + m], hiv);
    }
    #pragma unroll
    for (int r = 0; r < 4; ++r) {                 // pkW2T via vectorized f32x4 loads
        int g = r * NTHREADS + tid;               // [0,1024): kp in [0,32), colq in [0,16)
        int kp = g >> 4, colq = g & 15;
        f32x4 ra = *(const f32x4*)&W2[(2*kp)    *64 + colq*4];
        f32x4 rb = *(const f32x4*)&W2[(2*kp + 1)*64 + colq*4];
        #pragma unroll
        for (int c = 0; c < 4; ++c)
            pkW2T[(colq*4 + c)*33 + kp] = packtr(ra[c], rb[c]);
    }
    if (tid < 64) b2s[tid] = b2p[tid];
    __syncthreads();

    int lane = tid & 63, wv = tid >> 6;
    int lo16 = lane & 15, hi16 = lane >> 4;
    int plW0 = pl0b + wv * TW;
    int iW0  = e * PP + plW0;

    // EDST is search-independent: store early
    #pragma unroll
    for (int t = 0; t < TW; ++t)
        if (lane < KK) out[EDST_OFF + (iW0 + t) * KK + lane] = (float)(iW0 + t);

    // ---------------- Phase B: key build for two targets ----------------
    u32 key[TW][4];
    {
        float ax[TW], ay[TW], az[TW];
        #pragma unroll
        for (int t = 0; t < TW; ++t) {
            ax[t] = psl[(plW0+t)*3]; ay[t] = psl[(plW0+t)*3+1]; az[t] = psl[(plW0+t)*3+2];
        }
        #pragma unroll
        for (int q = 0; q < 4; ++q) {
            int j = lane + q * 64;
            int jc = (j < PP) ? j : 0;
            float px = psl[jc*3], py = psl[jc*3+1], pz = psl[jc*3+2];
            #pragma unroll
            for (int t = 0; t < TW; ++t) {
                float dx = px-ax[t], dy = py-ay[t], dz = pz-az[t];
                float d2 = dx*dx + dy*dy + dz*dz;
                key[t][q] = (j < PP && j != plW0 + t)
                          ? ((__float_as_uint(d2) & 0xFFFFFF00u) | (u32)j) : 0xFFFFFFFFu;
            }
        }
    }

    // ---- weight fragment loads issued HERE: the bisection below is pure
    // ballot/SALU (no lgkm), so these LDS loads complete under the search ----
    bf16x8 w1f[4];
    #pragma unroll
    for (int th = 0; th < 4; ++th) {
        union { u32 w[4]; bf16x8 v; } u;
        if (hi16 == 0) *(u32x4*)u.w = *(const u32x4*)&pkW1[(th * 16 + lo16) * 4];
        else { u.w[0] = u.w[1] = u.w[2] = u.w[3] = 0u; }
        w1f[th] = u.v;
    }
    bf16x8 bfr[4][2];
    #pragma unroll
    for (int t = 0; t < 4; ++t)
        #pragma unroll
        for (int s = 0; s < 2; ++s) {
            union { u32 w[4]; bf16x8 v; } u;
            int base = (t * 16 + lo16) * 33 + s * 16 + hi16 * 4;
            #pragma unroll
            for (int d = 0; d < 4; ++d) u.w[d] = pkW2T[base + d];
            bfr[t][s] = u.v;
        }
    float b2me = b2s[lane];

    // ---------------- branchless unroll-4 bisection ----------------
    // invariant: cnt(lo) < 60 <= cnt(hi); exit on cnt==60 or width<=1
    // (keys unique => width 1 implies cnt(hi)==60). 8x4 = 32 iters >= 31 worst.
    u32 lo[TW], hi[TW]; int done[TW];
    #pragma unroll
    for (int t = 0; t < TW; ++t) { lo[t] = 0u; hi[t] = 0x7F800000u; done[t] = 0; }
    #pragma unroll 1
    for (int g = 0; g < 8; ++g) {
        #pragma unroll
        for (int u4 = 0; u4 < 4; ++u4) {
            #pragma unroll
            for (int t = 0; t < TW; ++t) {
                u32 m = lo[t] + ((hi[t] - lo[t]) >> 1);
                int c = __builtin_popcountll(__ballot(key[t][0] < m))
                      + __builtin_popcountll(__ballot(key[t][1] < m))
                      + __builtin_popcountll(__ballot(key[t][2] < m))
                      + __builtin_popcountll(__ballot(key[t][3] < m));
                int upd = !done[t];
                int ge  = (c >= KK);
                hi[t] = (upd & ge)  ? m : hi[t];
                lo[t] = (upd & !ge) ? m : lo[t];
                done[t] |= (c == KK) | (hi[t] - lo[t] <= 1u);
            }
        }
        int alldone = done[0];
        #pragma unroll
        for (int t = 1; t < TW; ++t) alldone &= done[t];
        if (alldone) break;
    }

    // ---------------- compaction -> jslot; coalesced ESRC ----------------
    const int jsb = wv * (TW * 64);
    #pragma unroll
    for (int t = 0; t < TW; ++t) {
        if (lane >= KK) jslot[jsb + t * 64 + lane] = (u32)(plW0 + t);  // self slots
        u64 m0 = __ballot(key[t][0] < hi[t]);
        u64 m1 = __ballot(key[t][1] < hi[t]);
        u64 m2 = __ballot(key[t][2] < hi[t]);
        u64 m3 = __ballot(key[t][3] < hi[t]);
        u32 s1 = (u32)__builtin_popcountll(m0);
        u32 s2 = s1 + (u32)__builtin_popcountll(m1);
        u32 s3 = s2 + (u32)__builtin_popcountll(m2);
        u32 sl[4] = { prefix_lt(m0), s1 + prefix_lt(m1),
                      s2 + prefix_lt(m2), s3 + prefix_lt(m3) };
        #pragma unroll
        for (int q = 0; q < 4; ++q)
            if (key[t][q] < hi[t]) jslot[jsb + t * 64 + (int)sl[q]] = key[t][q] & 0xFFu;
    }
    #pragma unroll
    for (int t = 0; t < TW; ++t) {
        int i = iW0 + t;
        if (lane < KK)
            out[ESRC_OFF + i * KK + lane] = (float)(e * PP + (int)jslot[jsb + t * 64 + lane]);
    }

    // ---------------- Phase C: MLP + max-aggregate (per-tl msg) ----------------
    const int msb = wv * 256;
    const u32* mbase = (hi16 == 0) ? &msg[msb + lo16 * 4] : zrow;
    const int mstep  = (hi16 == 0) ? 64 : 0;

    for (int tl = 0; tl < TW; ++tl) {
        int i = iW0 + tl, pl = plW0 + tl;
        int jloc = (int)jslot[jsb + tl * 64 + lane];
        u32x2 xp = *(const u32x2*)&xsp[jloc * 2];     // pre-packed bf16 features
        float rx = psl[jloc*3]   - psl[pl*3];
        float ry = psl[jloc*3+1] - psl[pl*3+1];
        float rz = psl[jloc*3+2] - psl[pl*3+2];
        u32x4 mrow;
        mrow[0] = xp[0];
        mrow[1] = xp[1];
        mrow[2] = packtr(rx, ry);
        mrow[3] = packtr(rz, 1.0f);
        *(u32x4*)&msg[msb + lane * 4] = mrow;

        float rmax[4] = {-3.0e38f, -3.0e38f, -3.0e38f, -3.0e38f};
        __builtin_amdgcn_s_setprio(1);
        #pragma unroll
        for (int rt = 0; rt < 4; ++rt) {
            union { u32 w[4]; bf16x8 v; } mu;
            *(u32x4*)mu.w = *(const u32x4*)(mbase + rt * mstep);

            f32x4 c1[4];
            #pragma unroll
            for (int th = 0; th < 4; ++th)
                c1[th] = __builtin_amdgcn_mfma_f32_16x16x32_bf16(w1f[th], mu.v,
                                                                 (f32x4)0.f, 0, 0, 0);
            f32x4 acc[4];
            #pragma unroll
            for (int t = 0; t < 4; ++t) acc[t] = (f32x4)0.f;

            #pragma unroll
            for (int s = 0; s < 2; ++s) {
                u32 pe0 = packtr(fmaxf(c1[2*s][0], 0.f), fmaxf(c1[2*s][1], 0.f));
                u32 pe1 = packtr(fmaxf(c1[2*s][2], 0.f), fmaxf(c1[2*s][3], 0.f));
                u32 po0 = packtr(fmaxf(c1[2*s+1][0], 0.f), fmaxf(c1[2*s+1][1], 0.f));
                u32 po1 = packtr(fmaxf(c1[2*s+1][2], 0.f), fmaxf(c1[2*s+1][3], 0.f));
                // register repack (permlane32_swap + permlane16_swap), no LDS
                union { u32 w[4]; bf16x8 v; } u;
                {
                    auto t0 = __builtin_amdgcn_permlane32_swap(pe0, po0, false, false);
                    auto w0 = __builtin_amdgcn_permlane16_swap(t0[0], t0[1], false, false);
                    u.w[0] = w0[0]; u.w[2] = w0[1];
                }
                {
                    auto t1 = __builtin_amdgcn_permlane32_swap(pe1, po1, false, false);
                    auto w1 = __builtin_amdgcn_permlane16_swap(t1[0], t1[1], false, false);
                    u.w[1] = w1[0]; u.w[3] = w1[1];
                }
                #pragma unroll
                for (int t = 0; t < 4; ++t)
                    acc[t] = __builtin_amdgcn_mfma_f32_16x16x32_bf16(u.v, bfr[t][s],
                                                                     acc[t], 0, 0, 0);
            }
            #pragma unroll
            for (int t = 0; t < 4; ++t) {
                rmax[t] = fmaxf(fmaxf(acc[t][0], acc[t][1]), rmax[t]);
                rmax[t] = fmaxf(fmaxf(acc[t][2], acc[t][3]), rmax[t]);
            }
        }
        __builtin_amdgcn_s_setprio(0);
        #pragma unroll
        for (int t = 0; t < 4; ++t) rmax[t] = wavemax16(rmax[t]);
        float sel = rmax[0];
        sel = (hi16 == 1) ? rmax[1] : sel;
        sel = (hi16 == 2) ? rmax[2] : sel;
        sel = (hi16 == 3) ? rmax[3] : sel;
        out[OUT_OFF + i * 64 + lane] = fmaxf(sel + b2me, 0.f);
    }
}

// ---------------------------------------------------------------------------
extern "C" void kernel_launch(void* const* d_in, const int* in_sizes, int n_in,
                              void* d_out, int out_size, void* d_ws, size_t ws_size,
                              hipStream_t stream) {
    const float* x     = (const float*)d_in[0];
    const float* pos   = (const float*)d_in[1];
    const float* W1    = (const float*)d_in[3];
    const float* b1    = (const float*)d_in[4];
    const float* W2    = (const float*)d_in[5];
    const float* b2    = (const float*)d_in[6];
    float* out = (float*)d_out;
    (void)d_ws; (void)ws_size; (void)in_sizes; (void)n_in; (void)out_size;

    fused_kernel<<<dim3(NN / TB), dim3(NTHREADS), 0, stream>>>(x, pos, W1, b1, W2, b2, out);
}